// Round 9
// baseline (473.490 us; speedup 1.0000x reference)
//
#include <hip/hip_runtime.h>
#include <math.h>

// ---------------------------------------------------------------------------
// GCN 2-layer: per layer  out = Ahat @ (x @ W) + b, then erf-GELU.
// bf16 MFMA GEMMs (fp32 accum), atomic-free CSR fill, bf16 h/act1,
// mw=w*dinv[src] precompute, 8-deep gather unroll.
// This round: A/B test — histogram counters padded to 128B stride (one per
// L2 line) to relieve memory-side atomic line contention; init via memset.
// ---------------------------------------------------------------------------

#define HID 128
#define CPAD 32   // ints per counter slot (128 B)

typedef __attribute__((ext_vector_type(8))) short bf16x8;
typedef __attribute__((ext_vector_type(4))) float f32x4;

__device__ __forceinline__ unsigned short f2bf(float f) {
    unsigned int u = __float_as_uint(f);
    u = (u + 0x7fff + ((u >> 16) & 1)) >> 16;   // round-to-nearest-even
    return (unsigned short)u;
}
__device__ __forceinline__ float bfu2f(unsigned int lo16) {  // low 16 bits = bf16
    return __uint_as_float(lo16 << 16);
}

// ---- fused count + x->bf16 conversion -------------------------------------
__global__ __launch_bounds__(256) void count_cvt_kernel(
        const int* __restrict__ dst, int* __restrict__ count_pad,
        int* __restrict__ lpos, int E,
        const float* __restrict__ x, unsigned int* __restrict__ xb, long total8) {
    long g = (long)blockIdx.x * 256 + threadIdx.x;
    bool docvt = g < total8;
    float4 a, b;
    if (docvt) {
        const float4* p = reinterpret_cast<const float4*>(x + g * 8);
        a = p[0]; b = p[1];
    }
    int e = blockIdx.x * 256 + threadIdx.x;
    if (e < E) lpos[e] = atomicAdd(&count_pad[(size_t)dst[e] * CPAD], 1);
    if (docvt) {
        uint4 o;
        o.x = (unsigned int)f2bf(a.x) | ((unsigned int)f2bf(a.y) << 16);
        o.y = (unsigned int)f2bf(a.z) | ((unsigned int)f2bf(a.w) << 16);
        o.z = (unsigned int)f2bf(b.x) | ((unsigned int)f2bf(b.y) << 16);
        o.w = (unsigned int)f2bf(b.z) | ((unsigned int)f2bf(b.w) << 16);
        *reinterpret_cast<uint4*>(xb + g * 4) = o;
    }
}

// W[k][128] fp32 -> Wt[128][K] bf16 for both layers in one launch.
__global__ __launch_bounds__(256) void cvt_wt_kernel(const float* __restrict__ W1,
                                                     unsigned short* __restrict__ Wt1, int K1,
                                                     const float* __restrict__ W2,
                                                     unsigned short* __restrict__ Wt2, int K2) {
    int t = blockIdx.x * 256 + threadIdx.x;
    int n1 = 128 * K1;
    if (t < n1) {
        int k = t % K1, c = t / K1;
        Wt1[c * K1 + k] = f2bf(W1[(size_t)k * 128 + c]);
        return;
    }
    t -= n1;
    if (t < 128 * K2) {
        int k = t % K2, c = t / K2;
        Wt2[c * K2 + k] = f2bf(W2[(size_t)k * 128 + c]);
    }
}

// ---- CSR build ------------------------------------------------------------

__global__ __launch_bounds__(1024) void scan1_kernel(const int* __restrict__ count_pad,
                                                     int* __restrict__ row_start,
                                                     int* __restrict__ partials, int n) {
    __shared__ int sdata[1024];
    int t = threadIdx.x;
    int gid = blockIdx.x * 1024 + t;
    int v = (gid < n) ? count_pad[(size_t)gid * CPAD] : 0;
    sdata[t] = v;
    __syncthreads();
    for (int off = 1; off < 1024; off <<= 1) {
        int x = (t >= off) ? sdata[t - off] : 0;
        __syncthreads();
        sdata[t] += x;
        __syncthreads();
    }
    if (gid < n) row_start[gid] = sdata[t] - v;  // exclusive
    if (t == 1023) partials[blockIdx.x] = sdata[t];
}

__global__ __launch_bounds__(1024) void scan2_kernel(int* partials, int nparts) {
    __shared__ int sdata[1024];
    int t = threadIdx.x;
    int v = (t < nparts) ? partials[t] : 0;
    sdata[t] = v;
    __syncthreads();
    for (int off = 1; off < 1024; off <<= 1) {
        int x = (t >= off) ? sdata[t - off] : 0;
        __syncthreads();
        sdata[t] += x;
        __syncthreads();
    }
    if (t < nparts) partials[t] = sdata[t] - v;  // exclusive
}

__global__ __launch_bounds__(256) void finalize_kernel(const int* __restrict__ partials,
                                                       int* __restrict__ row_start,
                                                       int n, int E) {
    int i = blockIdx.x * 256 + threadIdx.x;
    if (i < n) row_start[i] += partials[i >> 10];
    if (i == 0) row_start[n] = E;
}

// Atomic-free scatter using saved local positions. Stores (src, raw w).
__global__ __launch_bounds__(256) void fill_kernel(const int* __restrict__ src,
                                                   const int* __restrict__ dst,
                                                   const float* __restrict__ w,
                                                   const int* __restrict__ row_start,
                                                   const int* __restrict__ lpos,
                                                   uint2* __restrict__ csr_sw, int E) {
    int e = blockIdx.x * 256 + threadIdx.x;
    if (e >= E) return;
    int d = dst[e];
    int pos = row_start[d] + lpos[e];
    csr_sw[pos] = make_uint2((unsigned int)src[e], __float_as_uint(w[e]));
}

__global__ __launch_bounds__(256) void dinv_kernel(const uint2* __restrict__ csr_sw,
                                                   const int* __restrict__ row_start,
                                                   float* __restrict__ dinv, int n) {
    int i = blockIdx.x * 256 + threadIdx.x;
    if (i >= n) return;
    float dsum = 1.0f;
    int e1 = row_start[i + 1];
    for (int e = row_start[i]; e < e1; e++) dsum += __uint_as_float(csr_sw[e].y);
    dinv[i] = rsqrtf(dsum);
}

// In-place: csr.y <- w * dinv[src].
__global__ __launch_bounds__(256) void mw_kernel(uint2* __restrict__ csr_sw,
                                                 const float* __restrict__ dinv, int E) {
    int e = blockIdx.x * 256 + threadIdx.x;
    if (e >= E) return;
    uint2 v = csr_sw[e];
    v.y = __float_as_uint(__uint_as_float(v.y) * dinv[v.x]);
    csr_sw[e] = v;
}

// ---------------------------------------------------------------------------
// MFMA GEMM: Hb[n][128] = Ab[n][K] @ Wt^T, bf16 in / fp32 accum / bf16 out.
// Tile 128x128, BK=32, 4 waves, 2x8 16x16x32 frags per wave.
// ---------------------------------------------------------------------------
template <int K>
__global__ __launch_bounds__(256) void gemm_mfma_kernel(
        const unsigned short* __restrict__ Ab,   // [n][K] bf16
        const unsigned short* __restrict__ Wt,   // [128][K] bf16 (transposed W)
        unsigned short* __restrict__ Hb,         // [n][128] bf16
        int n) {
    __shared__ unsigned short Asl[128][40];
    __shared__ unsigned short Btl[128][40];
    const int t = threadIdx.x;
    const int w = t >> 6;
    const int l = t & 63;
    const int lr = l & 15;
    const int ks = l >> 4;
    const int brow = blockIdx.x * 128;

    f32x4 acc[2][8];
#pragma unroll
    for (int m = 0; m < 2; m++)
#pragma unroll
        for (int j = 0; j < 8; j++) acc[m][j] = (f32x4)(0.f);

    for (int k0 = 0; k0 < K; k0 += 32) {
#pragma unroll
        for (int i = 0; i < 2; i++) {
            int idx = i * 256 + t;
            int r = idx >> 2;
            int c8 = idx & 3;
            int gr = brow + r;
            uint4 v = make_uint4(0u, 0u, 0u, 0u);
            if (gr < n) v = *reinterpret_cast<const uint4*>(&Ab[(size_t)gr * K + k0 + c8 * 8]);
            *reinterpret_cast<uint4*>(&Asl[r][c8 * 8]) = v;
        }
#pragma unroll
        for (int i = 0; i < 2; i++) {
            int idx = i * 256 + t;
            int r = idx >> 2;
            int c8 = idx & 3;
            uint4 v = *reinterpret_cast<const uint4*>(&Wt[(size_t)r * K + k0 + c8 * 8]);
            *reinterpret_cast<uint4*>(&Btl[r][c8 * 8]) = v;
        }
        __syncthreads();

        bf16x8 af[2];
#pragma unroll
        for (int m = 0; m < 2; m++)
            af[m] = *reinterpret_cast<const bf16x8*>(&Asl[w * 32 + m * 16 + lr][ks * 8]);
#pragma unroll
        for (int j = 0; j < 8; j++) {
            bf16x8 bfr = *reinterpret_cast<const bf16x8*>(&Btl[j * 16 + lr][ks * 8]);
            acc[0][j] = __builtin_amdgcn_mfma_f32_16x16x32_bf16(af[0], bfr, acc[0][j], 0, 0, 0);
            acc[1][j] = __builtin_amdgcn_mfma_f32_16x16x32_bf16(af[1], bfr, acc[1][j], 0, 0, 0);
        }
        __syncthreads();
    }

#pragma unroll
    for (int m = 0; m < 2; m++) {
#pragma unroll
        for (int r = 0; r < 4; r++) {
            int row = brow + w * 32 + m * 16 + ks * 4 + r;
            if (row < n) {
#pragma unroll
                for (int j = 0; j < 8; j++)
                    Hb[(size_t)row * 128 + j * 16 + lr] = f2bf(acc[m][j][r]);
            }
        }
    }
}

// ---------------------------------------------------------------------------
// Aggregate + bias + erf-GELU. One wave per node; lane c2 owns dims
// {2*c2, 2*c2+1}; (src, mw) CSR; 8-deep gather unroll.
// ---------------------------------------------------------------------------
template <bool BF16_OUT>
__global__ __launch_bounds__(256) void aggregate_gelu_kernel(
        const unsigned int* __restrict__ hb,   // bf16 pairs, [n][64]
        const int* __restrict__ row_start,
        const uint2* __restrict__ csr_sw,      // (src, mw)
        const float* __restrict__ dinv,
        const float* __restrict__ bias,
        unsigned int* __restrict__ outb,
        float* __restrict__ outf, int n) {
    int node = blockIdx.x * 4 + (threadIdx.x >> 6);
    int c2 = threadIdx.x & 63;
    if (node >= n) return;

    float di = dinv[node];
    float dd = di * di;
    float2 b2 = *reinterpret_cast<const float2*>(&bias[c2 * 2]);
    unsigned int self = hb[(size_t)node * 64 + c2];
    float s0 = 0.f, s1 = 0.f;

    int e = row_start[node];
    const int e1 = row_start[node + 1];

    for (; e + 8 <= e1; e += 8) {
        uint2 ew[8];
#pragma unroll
        for (int i = 0; i < 8; i++) ew[i] = csr_sw[e + i];
        unsigned int v[8];
#pragma unroll
        for (int i = 0; i < 8; i++) v[i] = hb[(size_t)ew[i].x * 64 + c2];
#pragma unroll
        for (int i = 0; i < 8; i++) {
            float m = __uint_as_float(ew[i].y);
            s0 += m * bfu2f(v[i] & 0xffffu);
            s1 += m * bfu2f(v[i] >> 16);
        }
    }
    if (e + 4 <= e1) {
        uint2 ew[4];
#pragma unroll
        for (int i = 0; i < 4; i++) ew[i] = csr_sw[e + i];
        unsigned int v[4];
#pragma unroll
        for (int i = 0; i < 4; i++) v[i] = hb[(size_t)ew[i].x * 64 + c2];
#pragma unroll
        for (int i = 0; i < 4; i++) {
            float m = __uint_as_float(ew[i].y);
            s0 += m * bfu2f(v[i] & 0xffffu);
            s1 += m * bfu2f(v[i] >> 16);
        }
        e += 4;
    }
    for (; e < e1; e++) {
        uint2 ew = csr_sw[e];
        float m = __uint_as_float(ew.y);
        unsigned int v = hb[(size_t)ew.x * 64 + c2];
        s0 += m * bfu2f(v & 0xffffu);
        s1 += m * bfu2f(v >> 16);
    }

    float acc0 = b2.x + dd * bfu2f(self & 0xffffu) + di * s0;
    float acc1 = b2.y + dd * bfu2f(self >> 16) + di * s1;
    float g0 = 0.5f * acc0 * (1.0f + erff(acc0 * 0.70710678118654752f));
    float g1 = 0.5f * acc1 * (1.0f + erff(acc1 * 0.70710678118654752f));
    if (BF16_OUT) {
        outb[(size_t)node * 64 + c2] =
            (unsigned int)f2bf(g0) | ((unsigned int)f2bf(g1) << 16);
    } else {
        *reinterpret_cast<float2*>(&outf[(size_t)node * 128 + c2 * 2]) = make_float2(g0, g1);
    }
}

// ---------------------------------------------------------------------------

extern "C" void kernel_launch(void* const* d_in, const int* in_sizes, int n_in,
                              void* d_out, int out_size, void* d_ws, size_t ws_size,
                              hipStream_t stream) {
    const float* x  = (const float*)d_in[0];
    const int*   ei = (const int*)d_in[1];
    const float* ew = (const float*)d_in[2];
    const float* W1 = (const float*)d_in[3];
    const float* b1 = (const float*)d_in[4];
    const float* W2 = (const float*)d_in[5];
    const float* b2 = (const float*)d_in[6];

    const int IN = 256;
    const int n = in_sizes[0] / IN;
    const int E = in_sizes[2];
    const int* src = ei;
    const int* dst = ei + E;

    char* wsb = (char*)d_ws;
    size_t off = 0;
    auto alloc = [&](size_t bytes) -> void* {
        void* p = wsb + off;
        off = (off + bytes + 255) & ~(size_t)255;
        return p;
    };
    int*   count_pad = (int*)alloc((size_t)n * CPAD * 4);   // 128 B per counter
    int*   lpos      = (int*)alloc((size_t)E * 4);
    int*   row_start = (int*)alloc((size_t)(n + 1) * 4);
    int*   partials  = (int*)alloc(4096);
    float* dinv      = (float*)alloc((size_t)n * 4);
    uint2* csr_sw    = (uint2*)alloc((size_t)E * 8);
    unsigned short* hb  = (unsigned short*)alloc((size_t)n * HID * 2);  // bf16 h
    unsigned short* wt1 = (unsigned short*)alloc((size_t)128 * IN * 2);
    unsigned short* wt2 = (unsigned short*)alloc((size_t)128 * HID * 2);

    // xb (bf16 x) and act1b (bf16 act1) live inside d_out (see round 5 note).
    unsigned short* xb    = (unsigned short*)d_out;
    unsigned short* act1b = (unsigned short*)d_out;
    float* out = (float*)d_out;

    const int nscan = (n + 1023) / 1024;
    long total8 = (long)n * IN / 8;
    int cvtBlocks = (int)((total8 + 255) / 256);
    int fusedBlocks = cvtBlocks > (E + 255) / 256 ? cvtBlocks : (E + 255) / 256;

    hipMemsetAsync(count_pad, 0, (size_t)n * CPAD * 4, stream);
    hipLaunchKernelGGL(count_cvt_kernel, dim3(fusedBlocks), dim3(256), 0, stream,
                       dst, count_pad, lpos, E, x, (unsigned int*)xb, total8);
    hipLaunchKernelGGL(cvt_wt_kernel, dim3((128 * IN + 128 * HID + 255) / 256), dim3(256),
                       0, stream, W1, wt1, IN, W2, wt2, HID);
    hipLaunchKernelGGL(scan1_kernel, dim3(nscan), dim3(1024), 0, stream,
                       count_pad, row_start, partials, n);
    hipLaunchKernelGGL(scan2_kernel, dim3(1), dim3(1024), 0, stream, partials, nscan);
    hipLaunchKernelGGL(finalize_kernel, dim3((n + 255) / 256), dim3(256), 0, stream,
                       partials, row_start, n, E);
    hipLaunchKernelGGL(fill_kernel, dim3((E + 255) / 256), dim3(256), 0, stream,
                       src, dst, ew, row_start, lpos, csr_sw, E);
    hipLaunchKernelGGL(dinv_kernel, dim3((n + 255) / 256), dim3(256), 0, stream,
                       csr_sw, row_start, dinv, n);
    hipLaunchKernelGGL(mw_kernel, dim3((E + 255) / 256), dim3(256), 0, stream,
                       csr_sw, dinv, E);

    // layer 1: mfma gemm (xb -> hb) ; aggregate -> act1b (bf16, in d_out)
    hipLaunchKernelGGL((gemm_mfma_kernel<256>), dim3((n + 127) / 128), dim3(256), 0, stream,
                       xb, wt1, hb, n);
    hipLaunchKernelGGL((aggregate_gelu_kernel<true>), dim3((n + 3) / 4), dim3(256), 0, stream,
                       (const unsigned int*)hb, row_start, csr_sw, dinv, b1,
                       (unsigned int*)act1b, nullptr, n);
    // layer 2: mfma gemm (act1b -> hb) ; aggregate -> out (fp32)
    hipLaunchKernelGGL((gemm_mfma_kernel<128>), dim3((n + 127) / 128), dim3(256), 0, stream,
                       act1b, wt2, hb, n);
    hipLaunchKernelGGL((aggregate_gelu_kernel<false>), dim3((n + 3) / 4), dim3(256), 0, stream,
                       (const unsigned int*)hb, row_start, csr_sw, dinv, b2,
                       nullptr, out, n);
}